// Round 6
// baseline (1422.696 us; speedup 1.0000x reference)
//
#include <hip/hip_runtime.h>
#include <cstdint>
#include <cstddef>

// ---------- types ----------
typedef _Float16 half2v __attribute__((ext_vector_type(2)));
typedef _Float16 half4v __attribute__((ext_vector_type(4)));
typedef _Float16 half8v __attribute__((ext_vector_type(8)));
typedef float f32x4 __attribute__((ext_vector_type(4)));

__device__ __forceinline__ float sigm(float x) { return 1.0f / (1.0f + __expf(-x)); }
__device__ __forceinline__ float tanh_(float x) { return 1.0f - 2.0f / (__expf(2.0f * x) + 1.0f); }

// Problem constants
#define BB 128
#define TT 512
#define II 300
#define IIP 320   // padded K for fp16 path
#define HH 256
#define GG 1024  // 4*H

// ============================================================================
// Kernel 0: convert X (65536x300 f32) and W_ih_f (1024x300 f32) to fp16 with
// zero-padded K=320 rows, enabling 16B-aligned global_load_lds in the GEMM.
// ============================================================================
__global__ __launch_bounds__(256) void cvt_xw(
    const float* __restrict__ X, const float* __restrict__ W,
    _Float16* __restrict__ Xh, _Float16* __restrict__ Wh)
{
    const int total = (65536 + 1024) * 40;   // 8-elem chunks per padded row
    for (int c = blockIdx.x * 256 + threadIdx.x; c < total; c += gridDim.x * 256) {
        const int row = c / 40;
        const int ch = c - row * 40;
        const int k0 = ch * 8;
        const float* src;
        _Float16* dst;
        if (row < 65536) {
            src = X + (size_t)row * II;
            dst = Xh + (size_t)row * IIP;
        } else {
            src = W + (size_t)(row - 65536) * II;
            dst = Wh + (size_t)(row - 65536) * IIP;
        }
        half8v hv;
        if (k0 + 8 <= II) {
            float4 a = *(const float4*)(src + k0);
            float4 b = *(const float4*)(src + k0 + 4);
            hv = half8v{(_Float16)a.x, (_Float16)a.y, (_Float16)a.z, (_Float16)a.w,
                        (_Float16)b.x, (_Float16)b.y, (_Float16)b.z, (_Float16)b.w};
        } else {
#pragma unroll
            for (int q = 0; q < 8; ++q) {
                const int k = k0 + q;
                hv[q] = (k < II) ? (_Float16)src[k] : (_Float16)0.f;
            }
        }
        *(half8v*)(dst + k0) = hv;
    }
}

// ============================================================================
// Kernel 1b: xp GEMM, fp16 inputs via global_load_lds (m97 structure). PROVEN.
// ============================================================================
#if __has_builtin(__builtin_amdgcn_global_load_lds)
#define HAVE_GLL 1
__device__ __forceinline__ void gll16(const _Float16* g, _Float16* l) {
    __builtin_amdgcn_global_load_lds(
        (const __attribute__((address_space(1))) void*)g,
        (__attribute__((address_space(3))) void*)l, 16, 0, 0);
}
#else
#define HAVE_GLL 0
#endif

__global__ __launch_bounds__(256) void gemm_xp_h(
    const _Float16* __restrict__ Xh, const _Float16* __restrict__ Wh,
    const float* __restrict__ bias, _Float16* __restrict__ XP)
{
    __shared__ __align__(16) _Float16 As[128 * 32];
    __shared__ __align__(16) _Float16 Bs[128 * 32];

    const int t = threadIdx.x;
    const int m0 = blockIdx.y * 128;
    const int n0 = blockIdx.x * 128;
    const int lane = t & 63;
    const int wv = t >> 6;
    const int mq = (wv >> 1) * 4;
    const int nq = (wv & 1) * 4;

    int rowd[2], k4d[2], cidx[2];
#pragma unroll
    for (int r = 0; r < 2; ++r) {
        const int c = wv * 128 + r * 64 + lane;
        cidx[r] = c;
        rowd[r] = ((c >> 6) << 4) | (c & 15);
        k4d[r] = (c >> 4) & 3;
    }

    f32x4 acc[4][4];
#pragma unroll
    for (int i = 0; i < 4; ++i)
#pragma unroll
        for (int j = 0; j < 4; ++j) acc[i][j] = f32x4{0.f, 0.f, 0.f, 0.f};

    for (int kc = 0; kc < IIP; kc += 32) {
        __syncthreads();
#pragma unroll
        for (int r = 0; r < 2; ++r) {
            const _Float16* ga = Xh + (size_t)(m0 + rowd[r]) * IIP + kc + k4d[r] * 8;
            const _Float16* gb = Wh + (size_t)(n0 + rowd[r]) * IIP + kc + k4d[r] * 8;
#if HAVE_GLL
            gll16(ga, &As[cidx[r] * 8]);
            gll16(gb, &Bs[cidx[r] * 8]);
#else
            *(half8v*)(&As[cidx[r] * 8]) = *(const half8v*)ga;
            *(half8v*)(&Bs[cidx[r] * 8]) = *(const half8v*)gb;
#endif
        }
        __syncthreads();

        half8v af[4], bf[4];
#pragma unroll
        for (int i = 0; i < 4; ++i) {
            af[i] = *(const half8v*)(&As[(mq + i) * 512 + (lane >> 4) * 128 + (lane & 15) * 8]);
            bf[i] = *(const half8v*)(&Bs[(nq + i) * 512 + (lane >> 4) * 128 + (lane & 15) * 8]);
        }
#pragma unroll
        for (int i = 0; i < 4; ++i)
#pragma unroll
            for (int j = 0; j < 4; ++j)
                acc[i][j] = __builtin_amdgcn_mfma_f32_16x16x32_f16(af[i], bf[j], acc[i][j], 0, 0, 0);
    }

#pragma unroll
    for (int j = 0; j < 4; ++j) {
        const int n = n0 + (nq + j) * 16 + (lane & 15);
        const float bv = bias[n];
#pragma unroll
        for (int i = 0; i < 4; ++i) {
#pragma unroll
            for (int r = 0; r < 4; ++r) {
                const int m = m0 + (mq + i) * 16 + (lane >> 4) * 4 + r;
                XP[(size_t)m * GG + n] = (_Float16)(acc[i][j][r] + bv);
            }
        }
    }
}

// ============================================================================
// Kernel 1 (fallback): xp GEMM from f32 inputs (the proven v1 kernel).
// ============================================================================
__global__ __launch_bounds__(256, 3) void gemm_xp(
    const float* __restrict__ X, const float* __restrict__ W,
    const float* __restrict__ bias, _Float16* __restrict__ XP)
{
    __shared__ _Float16 As[128 * 32];
    __shared__ _Float16 Bs[128 * 32];

    const int t = threadIdx.x;
    const int m0 = blockIdx.y * 128;
    const int n0 = blockIdx.x * 128;
    const int kpos = t & 7;
    const int rbase = t >> 3;
    const int lane = t & 63;
    const int wv = t >> 6;
    const int mq = (wv >> 1) * 4;
    const int nq = (wv & 1) * 4;

    f32x4 acc[4][4];
#pragma unroll
    for (int i = 0; i < 4; ++i)
#pragma unroll
        for (int j = 0; j < 4; ++j) acc[i][j] = f32x4{0.f, 0.f, 0.f, 0.f};

    for (int kc = 0; kc < 320; kc += 32) {
        __syncthreads();
        const int k0 = kc + kpos * 4;
#pragma unroll
        for (int rr = 0; rr < 4; ++rr) {
            const int row = rbase + rr * 32;
            float4 va = {0.f, 0.f, 0.f, 0.f}, vb = {0.f, 0.f, 0.f, 0.f};
            if (k0 < 300) {
                va = *(const float4*)(X + (size_t)(m0 + row) * II + k0);
                vb = *(const float4*)(W + (size_t)(n0 + row) * II + k0);
            }
            const int idx = (row >> 4) * 512 + (kpos >> 1) * 128 + (row & 15) * 8 + (kpos & 1) * 4;
            half4v ha = {(_Float16)va.x, (_Float16)va.y, (_Float16)va.z, (_Float16)va.w};
            half4v hb = {(_Float16)vb.x, (_Float16)vb.y, (_Float16)vb.z, (_Float16)vb.w};
            *(half4v*)(&As[idx]) = ha;
            *(half4v*)(&Bs[idx]) = hb;
        }
        __syncthreads();

        half8v af[4], bf[4];
#pragma unroll
        for (int i = 0; i < 4; ++i) {
            af[i] = *(const half8v*)(&As[(mq + i) * 512 + (lane >> 4) * 128 + (lane & 15) * 8]);
            bf[i] = *(const half8v*)(&Bs[(nq + i) * 512 + (lane >> 4) * 128 + (lane & 15) * 8]);
        }
#pragma unroll
        for (int i = 0; i < 4; ++i)
#pragma unroll
            for (int j = 0; j < 4; ++j)
                acc[i][j] = __builtin_amdgcn_mfma_f32_16x16x32_f16(af[i], bf[j], acc[i][j], 0, 0, 0);
    }

#pragma unroll
    for (int j = 0; j < 4; ++j) {
        const int n = n0 + (nq + j) * 16 + (lane & 15);
        const float bv = bias[n];
#pragma unroll
        for (int i = 0; i < 4; ++i) {
#pragma unroll
            for (int r = 0; r < 4; ++r) {
                const int m = m0 + (mq + i) * 16 + (lane >> 4) * 4 + r;
                XP[(size_t)m * GG + n] = (_Float16)(acc[i][j][r] + bv);
            }
        }
    }
}

// ============================================================================
// Kernel 2 (v6): forward recurrence via MFMA, M=1 per block, 128 blocks.
//
// Rationale: v1/v2/v5 showed the FDOT2 formulation stalls on dot-op dep
// latency (~4600 cyc/step regardless of LDS traffic). v4 proved the MFMA
// formulation is numerically correct AND 4.8x more cycle-efficient per
// batch-step (960 vs 4617), but died at 8 blocks (3% occupancy). v6 = v4's
// per-block schedule with M collapsed 16 -> 1: one batch element per block,
// 128 blocks (v1's proven occupancy). The A-operand is h broadcast to all
// 16 rows (every 16-lane group reads the same 16 B of h), so all 16 output
// rows compute the identical dot -- 15/16 of MFMA throughput wasted, still
// ~5x ahead of the VALU path, and zero dependency-chain stalls.
//
// Per wave: 8 col-tiles ct = gate*2 + jt covering cols gate*256 + w*32 +
// jt*16 + n16 (v4-proven mapping). B-frags: k-slices 0..5 resident in 192
// AGPR-backed regs; slices 6,7 in 128 KB LDS (v4-proven layout). Cell
// update on kq==0 lanes (acc[ct][0], rows all equal). h ping-pong: plain
// [2][256] fp16, ONE barrier/step.
// ============================================================================
__global__ __attribute__((amdgpu_flat_work_group_size(512, 512), amdgpu_waves_per_eu(2, 2)))
void lstm_fwd(
    const float* __restrict__ Whh, const _Float16* __restrict__ XP,
    float* __restrict__ HF)
{
    __shared__ __align__(16) _Float16 wlds[65536];   // 128 KB: [s][ntile][kq][n16][8]
    __shared__ __align__(16) _Float16 hl[2][HH];     // 1 KB ping-pong

    const int t = threadIdx.x;
    const int b = blockIdx.x;
    const int l = t & 63;
    const int w = t >> 6;            // wave 0..7
    const int n16 = l & 15;
    const int kq = l >> 4;           // 0..3

    // ---- resident B-fragments: slices ks=0..5 for 8 col-tiles (192 regs) ----
    half8v wr[8][6];
#pragma unroll
    for (int ct = 0; ct < 8; ++ct) {
        const int nct = (ct >> 1) * 256 + w * 32 + (ct & 1) * 16;
        const float* wp = Whh + (size_t)(nct + n16) * HH + kq * 8;
#pragma unroll
        for (int ks = 0; ks < 6; ++ks) {
            float4 a = *(const float4*)(wp + ks * 32);
            float4 c4 = *(const float4*)(wp + ks * 32 + 4);
            wr[ct][ks] = half8v{(_Float16)a.x, (_Float16)a.y, (_Float16)a.z, (_Float16)a.w,
                                (_Float16)c4.x, (_Float16)c4.y, (_Float16)c4.z, (_Float16)c4.w};
        }
    }
    // ---- LDS B-fragments: slices 6,7 (each thread fills 16 frag-slots) ----
#pragma unroll
    for (int i = 0; i < 16; ++i) {
        const int idx = i * 512 + t;          // 0..8191
        const int sn16 = idx & 15;
        const int skq = (idx >> 4) & 3;
        const int snt = (idx >> 6) & 63;
        const int ss  = (idx >> 12) & 1;
        const float* sp = Whh + (size_t)(snt * 16 + sn16) * HH + (6 + ss) * 32 + skq * 8;
        float4 a = *(const float4*)sp;
        float4 b4 = *(const float4*)(sp + 4);
        *(half8v*)(&wlds[idx * 8]) = half8v{(_Float16)a.x, (_Float16)a.y, (_Float16)a.z, (_Float16)a.w,
                                            (_Float16)b4.x, (_Float16)b4.y, (_Float16)b4.z, (_Float16)b4.w};
    }
    if (t < HH) hl[0][t] = (_Float16)0.f;
    float c0 = 0.f, c1 = 0.f;
    __syncthreads();

    // xp: per step, kq==0 lanes need cols g*256 + w*32 + jt*16 + n16
    const _Float16* xb = XP + (size_t)b * TT * GG + w * 32 + n16;
    _Float16 x[8];   // x[g*2+jt]
    if (kq == 0) {
#pragma unroll
        for (int g = 0; g < 4; ++g) {
            x[g * 2 + 0] = xb[g * 256];
            x[g * 2 + 1] = xb[g * 256 + 16];
        }
    }

    for (int ts = 0; ts < TT; ++ts) {
        const int p = ts & 1;
        const _Float16* hr = &hl[p][0];

        // prefetch next step's xp early (lands during this step's MFMAs)
        const _Float16* xn = xb + (size_t)((ts < TT - 1) ? ts + 1 : ts) * GG;
        _Float16 nx[8];
        if (kq == 0) {
#pragma unroll
            for (int g = 0; g < 4; ++g) {
                nx[g * 2 + 0] = xn[g * 256];
                nx[g * 2 + 1] = xn[g * 256 + 16];
            }
        }

        f32x4 acc[8];
#pragma unroll
        for (int ct = 0; ct < 8; ++ct) acc[ct] = f32x4{0.f, 0.f, 0.f, 0.f};

        // slices 0..5: B from registers; A = h broadcast (16B per kq group)
#pragma unroll
        for (int ks = 0; ks < 6; ++ks) {
            half8v A = *(const half8v*)(&hr[ks * 32 + kq * 8]);
#pragma unroll
            for (int ct = 0; ct < 8; ++ct)
                acc[ct] = __builtin_amdgcn_mfma_f32_16x16x32_f16(A, wr[ct][ks], acc[ct], 0, 0, 0);
        }
        // slices 6,7: B from LDS
#pragma unroll
        for (int s = 0; s < 2; ++s) {
            half8v A = *(const half8v*)(&hr[(6 + s) * 32 + kq * 8]);
#pragma unroll
            for (int ct = 0; ct < 8; ++ct) {
                const int nt = (ct >> 1) * 16 + w * 2 + (ct & 1);
                half8v Bv = *(const half8v*)(&wlds[(((s * 64 + nt) * 4 + kq) * 16 + n16) * 8]);
                acc[ct] = __builtin_amdgcn_mfma_f32_16x16x32_f16(A, Bv, acc[ct], 0, 0, 0);
            }
        }

        // cell update: rows of D all equal -> use reg 0 on kq==0 lanes
        if (kq == 0) {
#pragma unroll
            for (int jt = 0; jt < 2; ++jt) {
                const float gi = acc[0 + jt][0] + (float)x[0 + jt];
                const float gf = acc[2 + jt][0] + (float)x[2 + jt];
                const float gg = acc[4 + jt][0] + (float)x[4 + jt];
                const float go = acc[6 + jt][0] + (float)x[6 + jt];
                float cc = jt ? c1 : c0;
                cc = sigm(gf) * cc + sigm(gi) * tanh_(gg);
                if (jt) c1 = cc; else c0 = cc;
                const float h = sigm(go) * tanh_(cc);
                const int j = w * 32 + jt * 16 + n16;
                hl[p ^ 1][j] = (_Float16)h;
                if (ts == TT - 1) HF[(size_t)b * HH + j] = h;
            }
        }
        __syncthreads();

#pragma unroll
        for (int q = 0; q < 8; ++q) x[q] = nx[q];
    }
}

// ============================================================================
// Kernel 3: backward direction = ONE cell step on x[:, T-1] with h0=c0=0.
// ============================================================================
__global__ __launch_bounds__(256) void lstm_bwd(
    const float* __restrict__ X, const float* __restrict__ Wih,
    const float* __restrict__ bb, float* __restrict__ HB)
{
    __shared__ float xs[II];
    const int b = blockIdx.x, t = threadIdx.x;
    const float* xrow = X + ((size_t)b * TT + (TT - 1)) * II;
    if (t < 75) *(float4*)(&xs[t * 4]) = *(const float4*)(xrow + t * 4);
    __syncthreads();
    if (t < HH) {
        float ai = 0.f, ag = 0.f, ao = 0.f;
        const float4* wi = (const float4*)(Wih + (size_t)t * II);
        const float4* wg = (const float4*)(Wih + (size_t)(t + 512) * II);
        const float4* wo = (const float4*)(Wih + (size_t)(t + 768) * II);
        for (int k4 = 0; k4 < 75; ++k4) {
            float4 xv = *(const float4*)(&xs[k4 * 4]);
            float4 a = wi[k4], g4 = wg[k4], o4 = wo[k4];
            ai += xv.x * a.x + xv.y * a.y + xv.z * a.z + xv.w * a.w;
            ag += xv.x * g4.x + xv.y * g4.y + xv.z * g4.z + xv.w * g4.w;
            ao += xv.x * o4.x + xv.y * o4.y + xv.z * o4.z + xv.w * o4.w;
        }
        ai += bb[t];
        ag += bb[t + 512];
        ao += bb[t + 768];
        const float cg = sigm(ai) * tanh_(ag);
        HB[(size_t)b * HH + t] = sigm(ao) * tanh_(cg);
    }
}

// ============================================================================
// Kernel 4: out[b][jj] = [hf|hb] . W_lin[jj] + b_lin[jj]
// ============================================================================
__global__ __launch_bounds__(256) void final_k(
    const float* __restrict__ HF, const float* __restrict__ HB,
    const float* __restrict__ Wlin, const float* __restrict__ blin,
    float* __restrict__ OUT)
{
    const int t = threadIdx.x;
    const int b = t >> 1, jj = t & 1;
    float acc = blin[jj];
    const float* wf = Wlin + jj * 512;
    const float* wb = Wlin + jj * 512 + 256;
    const float* hf = HF + (size_t)b * HH;
    const float* hb = HB + (size_t)b * HH;
    for (int k = 0; k < HH; k += 4) {
        float4 h4 = *(const float4*)(hf + k);
        float4 w4 = *(const float4*)(wf + k);
        float4 g4 = *(const float4*)(hb + k);
        float4 v4 = *(const float4*)(wb + k);
        acc += h4.x * w4.x + h4.y * w4.y + h4.z * w4.z + h4.w * w4.w;
        acc += g4.x * v4.x + g4.y * v4.y + g4.z * v4.z + g4.w * v4.w;
    }
    OUT[b * 2 + jj] = acc;
}

// ============================================================================
extern "C" void kernel_launch(void* const* d_in, const int* in_sizes, int n_in,
                              void* d_out, int out_size, void* d_ws, size_t ws_size,
                              hipStream_t stream)
{
    const float* x = (const float*)d_in[0];
    const float* Wihf = (const float*)d_in[1];
    const float* Whhf = (const float*)d_in[2];
    const float* bf = (const float*)d_in[3];
    const float* Wihb = (const float*)d_in[4];
    const float* Whhb = (const float*)d_in[5];
    const float* bbv = (const float*)d_in[6];
    const float* Wlin = (const float*)d_in[7];
    const float* blin = (const float*)d_in[8];
    float* out = (float*)d_out;
    (void)Whhb; (void)in_sizes; (void)n_in; (void)out_size;

    // workspace layout: xp fp16 | hf f32 | hb f32 | Xh fp16 | Wh fp16
    const size_t XP_B = (size_t)BB * TT * GG * 2;            // 134,217,728
    const size_t H_B  = (size_t)BB * HH * 4;                 // 131,072
    const size_t XH_B = (size_t)65536 * IIP * 2;             // 41,943,040
    const size_t WH_B = (size_t)GG * IIP * 2;                // 655,360

    _Float16* xp = (_Float16*)d_ws;
    float* hf = (float*)((char*)d_ws + XP_B);
    float* hb = hf + (size_t)BB * HH;
    _Float16* Xh = (_Float16*)((char*)d_ws + XP_B + 2 * H_B);
    _Float16* Wh = Xh + (size_t)65536 * IIP;

    lstm_bwd<<<BB, 256, 0, stream>>>(x, Wihb, bbv, hb);
    if (ws_size >= XP_B + 2 * H_B + XH_B + WH_B) {
        cvt_xw<<<2048, 256, 0, stream>>>(x, Wihf, Xh, Wh);
        gemm_xp_h<<<dim3(GG / 128, (BB * TT) / 128), 256, 0, stream>>>(Xh, Wh, bf, xp);
    } else {
        gemm_xp<<<dim3(GG / 128, (BB * TT) / 128), 256, 0, stream>>>(x, Wihf, bf, xp);
    }
    lstm_fwd<<<BB, 512, 0, stream>>>(Whhf, xp, hf);
    final_k<<<1, 256, 0, stream>>>(hf, hb, Wlin, blin, out);
}